// Round 1
// baseline (6812.287 us; speedup 1.0000x reference)
//
#include <hip/hip_runtime.h>

typedef unsigned short ushort_t;
typedef __bf16 bf16x8 __attribute__((ext_vector_type(8)));
typedef float f32x4 __attribute__((ext_vector_type(4)));

// ---------- helpers ----------
__device__ __forceinline__ ushort_t f2bf(float f) {
    unsigned int u = __float_as_uint(f);
    u += 0x7FFFu + ((u >> 16) & 1u);          // RNE
    return (ushort_t)(u >> 16);
}
__device__ __forceinline__ float bf2f(ushort_t u) {
    return __uint_as_float(((unsigned int)u) << 16);
}
__device__ __forceinline__ float gelu_tanh(float x) {
    float x3 = x * x * x;
    float u = 0.7978845608028654f * (x + 0.044715f * x3);
    return 0.5f * x * (1.0f + tanhf(u));
}
__device__ __forceinline__ void store_out(float* p, float v)    { *p = v; }
__device__ __forceinline__ void store_out(ushort_t* p, float v) { *p = f2bf(v); }

// ---------- weight transpose + fp32->bf16:  W[K][N] -> WT[N][K] ----------
__global__ __launch_bounds__(256) void wtrans_k(const float* __restrict__ W,
                                                ushort_t* __restrict__ WT,
                                                int K, int N) {
    int nk = K >> 3;
    int total = (N >> 6) * nk;
    int gw = (blockIdx.x * 256 + threadIdx.x) >> 6;
    int nw = (gridDim.x * 256) >> 6;
    int lane = threadIdx.x & 63;
    for (int c = gw; c < total; c += nw) {
        int kb = c % nk, nb = c / nk;
        int n = nb * 64 + lane, k0 = kb * 8;
        ushort_t t0 = f2bf(W[(k0 + 0) * N + n]);
        ushort_t t1 = f2bf(W[(k0 + 1) * N + n]);
        ushort_t t2 = f2bf(W[(k0 + 2) * N + n]);
        ushort_t t3 = f2bf(W[(k0 + 3) * N + n]);
        ushort_t t4 = f2bf(W[(k0 + 4) * N + n]);
        ushort_t t5 = f2bf(W[(k0 + 5) * N + n]);
        ushort_t t6 = f2bf(W[(k0 + 6) * N + n]);
        ushort_t t7 = f2bf(W[(k0 + 7) * N + n]);
        int4 pk;
        pk.x = (int)t0 | ((int)t1 << 16);
        pk.y = (int)t2 | ((int)t3 << 16);
        pk.z = (int)t4 | ((int)t5 << 16);
        pk.w = (int)t6 | ((int)t7 << 16);
        *(int4*)(WT + n * K + k0) = pk;
    }
}

// ---------- W_out (V,D,PH,PW) -> WT[v*16+p*4+q][d]  (fp32) ----------
__global__ void wouttrans_k(const float* __restrict__ W_out, float* __restrict__ WT) {
    int i = blockIdx.x * 256 + threadIdx.x;
    if (i >= 32 * 768) return;
    int o = i / 768, d = i - o * 768;
    int v = o >> 4, p = (o >> 2) & 3, q = o & 3;
    WT[i] = W_out[((v * 768 + d) * 4 + p) * 4 + q];
}

// ---------- fp32 -> bf16 convert (vectorized) ----------
__global__ void convbf_k(const float* __restrict__ src, ushort_t* __restrict__ dst, int nq) {
    int i = blockIdx.x * 256 + threadIdx.x;
    int stride = gridDim.x * 256;
    for (; i < nq; i += stride) {
        float4 v = *(const float4*)(src + i * 4);
        int2 pk;
        pk.x = (int)f2bf(v.x) | ((int)f2bf(v.y) << 16);
        pk.y = (int)f2bf(v.z) | ((int)f2bf(v.w) << 16);
        *(int2*)(dst + i * 4) = pk;
    }
}

// ---------- embedding: patch einsum + mask + pos_emb -> x (fp32) ----------
__global__ __launch_bounds__(256) void embed_k(const float* __restrict__ fields,
                                               const int* __restrict__ visible,
                                               const float* __restrict__ W_in,
                                               const float* __restrict__ mask_emb,
                                               const float* __restrict__ pos_emb,
                                               float* __restrict__ x) {
    int bid = blockIdx.x;               // be*512 + n
    int be = bid >> 9, n = bid & 511;
    int b = be >> 1;                    // E = 2
    int hh = n >> 5, w = n & 31;
    __shared__ float fs[32];
    int t = threadIdx.x;
    if (t < 32) {
        int v = t >> 4, p = (t >> 2) & 3, q = t & 3;
        fs[t] = fields[((b * 2 + v) * 64 + hh * 4 + p) * 128 + w * 4 + q];
    }
    __syncthreads();
    int vis = visible[b * 512 + n];
    for (int d = t; d < 768; d += 256) {
        float a;
        if (vis) {
            a = 0.f;
            #pragma unroll
            for (int j = 0; j < 32; j++) a += fs[j] * W_in[j * 768 + d];
        } else {
            a = mask_emb[d];
        }
        x[(be * 512 + n) * 768 + d] = a + pos_emb[n * 768 + d];
    }
}

// ---------- LayerNorm: fp32 x -> bf16 h (1 wave / row) ----------
__global__ __launch_bounds__(256) void ln_k(const float* __restrict__ x,
                                            const float* __restrict__ s,
                                            const float* __restrict__ b,
                                            ushort_t* __restrict__ h) {
    int row = blockIdx.x * 4 + (threadIdx.x >> 6);
    int lane = threadIdx.x & 63;
    const float* xr = x + row * 768;
    float4 v[3];
    #pragma unroll
    for (int i = 0; i < 3; i++) v[i] = *(const float4*)(xr + (lane + 64 * i) * 4);
    float sum = 0.f;
    #pragma unroll
    for (int i = 0; i < 3; i++) sum += v[i].x + v[i].y + v[i].z + v[i].w;
    #pragma unroll
    for (int off = 32; off; off >>= 1) sum += __shfl_xor(sum, off);
    float mu = sum * (1.f / 768.f);
    float vs = 0.f;
    #pragma unroll
    for (int i = 0; i < 3; i++) {
        float dx = v[i].x - mu, dy = v[i].y - mu, dz = v[i].z - mu, dw = v[i].w - mu;
        vs += dx * dx + dy * dy + dz * dz + dw * dw;
    }
    #pragma unroll
    for (int off = 32; off; off >>= 1) vs += __shfl_xor(vs, off);
    float rstd = rsqrtf(vs * (1.f / 768.f) + 1e-5f);
    #pragma unroll
    for (int i = 0; i < 3; i++) {
        int c = (lane + 64 * i) * 4;
        float4 sv = *(const float4*)(s + c);
        float4 bv = *(const float4*)(b + c);
        int2 pk;
        pk.x = (int)f2bf((v[i].x - mu) * rstd * sv.x + bv.x)
             | ((int)f2bf((v[i].y - mu) * rstd * sv.y + bv.y) << 16);
        pk.y = (int)f2bf((v[i].z - mu) * rstd * sv.z + bv.z)
             | ((int)f2bf((v[i].w - mu) * rstd * sv.w + bv.w) << 16);
        *(int2*)(h + row * 768 + c) = pk;
    }
}

// ---------- bf16 MFMA GEMM:  out = epi(A[M][K] @ BT[N][K]^T + bias (+res)) ----------
template <typename OutT, bool RES, bool GELU>
__global__ __launch_bounds__(256) void gemm_bt(const ushort_t* __restrict__ A,
                                               const ushort_t* __restrict__ BT,
                                               const float* __restrict__ bias,
                                               const float* __restrict__ res,
                                               OutT* __restrict__ out,
                                               int M, int N, int K) {
    __shared__ ushort_t As[128][40];   // stride 40 elems (80B) -> ~2-way LDS conflicts (free)
    __shared__ ushort_t Bs[128][40];
    int t = threadIdx.x;
    int lane = t & 63;
    int wid = t >> 6;
    int wr = wid >> 1, wc = wid & 1;   // 2x2 waves, 64x64 out each
    int m0 = blockIdx.y * 128, n0 = blockIdx.x * 128;
    f32x4 acc[4][4];
    #pragma unroll
    for (int m = 0; m < 4; m++)
        #pragma unroll
        for (int n = 0; n < 4; n++) acc[m][n] = (f32x4){0.f, 0.f, 0.f, 0.f};

    int sr = t >> 2;            // 0..63
    int sk = (t & 3) * 8;       // 0,8,16,24
    for (int k0 = 0; k0 < K; k0 += 32) {
        int4 a0 = *(const int4*)(A + (m0 + sr) * K + k0 + sk);
        int4 a1 = *(const int4*)(A + (m0 + sr + 64) * K + k0 + sk);
        int4 b0 = *(const int4*)(BT + (n0 + sr) * K + k0 + sk);
        int4 b1 = *(const int4*)(BT + (n0 + sr + 64) * K + k0 + sk);
        __syncthreads();                       // protect prev-iter fragment reads
        *(int4*)(&As[sr][sk]) = a0;
        *(int4*)(&As[sr + 64][sk]) = a1;
        *(int4*)(&Bs[sr][sk]) = b0;
        *(int4*)(&Bs[sr + 64][sk]) = b1;
        __syncthreads();                       // publish
        bf16x8 af[4], bf[4];
        #pragma unroll
        for (int m = 0; m < 4; m++)
            af[m] = *(const bf16x8*)(&As[wr * 64 + m * 16 + (lane & 15)][(lane >> 4) * 8]);
        #pragma unroll
        for (int n = 0; n < 4; n++)
            bf[n] = *(const bf16x8*)(&Bs[wc * 64 + n * 16 + (lane & 15)][(lane >> 4) * 8]);
        #pragma unroll
        for (int m = 0; m < 4; m++)
            #pragma unroll
            for (int n = 0; n < 4; n++)
                acc[m][n] = __builtin_amdgcn_mfma_f32_16x16x32_bf16(af[m], bf[n], acc[m][n], 0, 0, 0);
    }
    __syncthreads();
    int rq = lane >> 4, cl = lane & 15;
    #pragma unroll
    for (int m = 0; m < 4; m++) {
        #pragma unroll
        for (int n = 0; n < 4; n++) {
            int col = n0 + wc * 64 + n * 16 + cl;
            float bv = bias[col];
            #pragma unroll
            for (int r = 0; r < 4; r++) {
                int row = m0 + wr * 64 + m * 16 + rq * 4 + r;
                float v = acc[m][n][r] + bv;
                if (RES) v += res[row * N + col];
                if (GELU) v = gelu_tanh(v);
                store_out(out + row * N + col, v);
            }
        }
    }
}

// ---------- attention (fp32 vector): qkv bf16 [8192][2304] -> o bf16 [8192][768] ----------
__global__ __launch_bounds__(256) void attn_k(const ushort_t* __restrict__ qkv,
                                              ushort_t* __restrict__ o) {
    int bid = blockIdx.x;
    int rt = bid & 31;                 // q-row tile (16 rows)
    int beh = bid >> 5;
    int h = beh % 12;
    int be = beh / 12;
    int t = threadIdx.x;
    int rr = t >> 4, c4 = t & 15;
    __shared__ float Qs[16][68];
    __shared__ float Ks[16][68];
    __shared__ float S[16][520];
    __shared__ float rinv[16];
    {
        ushort4 qv = *(const ushort4*)(qkv + (be * 512 + rt * 16 + rr) * 2304 + h * 64 + c4 * 4);
        Qs[rr][c4 * 4 + 0] = bf2f(qv.x);
        Qs[rr][c4 * 4 + 1] = bf2f(qv.y);
        Qs[rr][c4 * 4 + 2] = bf2f(qv.z);
        Qs[rr][c4 * 4 + 3] = bf2f(qv.w);
    }
    for (int ct = 0; ct < 32; ct++) {
        ushort4 kv = *(const ushort4*)(qkv + (be * 512 + ct * 16 + rr) * 2304 + 768 + h * 64 + c4 * 4);
        __syncthreads();               // prev scores done with Ks
        Ks[rr][c4 * 4 + 0] = bf2f(kv.x);
        Ks[rr][c4 * 4 + 1] = bf2f(kv.y);
        Ks[rr][c4 * 4 + 2] = bf2f(kv.z);
        Ks[rr][c4 * 4 + 3] = bf2f(kv.w);
        __syncthreads();
        float a = 0.f;
        #pragma unroll
        for (int kk = 0; kk < 16; kk++) {
            float4 q4 = *(const float4*)(&Qs[rr][kk * 4]);
            float4 k4 = *(const float4*)(&Ks[c4][kk * 4]);
            a += q4.x * k4.x + q4.y * k4.y + q4.z * k4.z + q4.w * k4.w;
        }
        S[rr][ct * 16 + c4] = a * 0.125f;
    }
    __syncthreads();
    {
        int wid = t >> 6, lane = t & 63;
        for (int r = wid; r < 16; r += 4) {
            float vals[8];
            float m = -3.4e38f;
            #pragma unroll
            for (int i = 0; i < 8; i++) { vals[i] = S[r][lane + 64 * i]; m = fmaxf(m, vals[i]); }
            #pragma unroll
            for (int off = 32; off; off >>= 1) m = fmaxf(m, __shfl_xor(m, off));
            float sum = 0.f;
            #pragma unroll
            for (int i = 0; i < 8; i++) {
                float e = __expf(vals[i] - m);
                S[r][lane + 64 * i] = e;
                sum += e;
            }
            #pragma unroll
            for (int off = 32; off; off >>= 1) sum += __shfl_xor(sum, off);
            if (lane == 0) rinv[r] = 1.f / sum;
        }
    }
    __syncthreads();
    {
        float ax = 0.f, ay = 0.f, az = 0.f, aw = 0.f;
        const ushort_t* vp = qkv + be * 512 * 2304 + 1536 + h * 64 + c4 * 4;
        for (int c = 0; c < 512; c++) {
            float p = S[rr][c];
            ushort4 vv = *(const ushort4*)(vp + c * 2304);
            ax += p * bf2f(vv.x);
            ay += p * bf2f(vv.y);
            az += p * bf2f(vv.z);
            aw += p * bf2f(vv.w);
        }
        float ri = rinv[rr];
        ushort4 ov;
        ov.x = f2bf(ax * ri); ov.y = f2bf(ay * ri); ov.z = f2bf(az * ri); ov.w = f2bf(aw * ri);
        *(ushort4*)(o + (be * 512 + rt * 16 + rr) * 768 + h * 64 + c4 * 4) = ov;
    }
}

// ---------- output projection ----------
__global__ __launch_bounds__(256) void outproj_k(const float* __restrict__ x,
                                                 const float* __restrict__ WT,
                                                 float* __restrict__ out) {
    int bid = blockIdx.x;              // be*512 + n
    int be = bid >> 9, n = bid & 511;
    __shared__ float xs[768];
    int t = threadIdx.x;
    if (t < 192) *(float4*)(&xs[t * 4]) = *(const float4*)(x + bid * 768 + t * 4);
    __syncthreads();
    int o = t >> 3, part = t & 7;      // 32 outputs x 8 partial threads
    float a = 0.f;
    #pragma unroll
    for (int i = 0; i < 24; i++) {
        int d = (part + 8 * i) * 4;
        float4 xv = *(const float4*)(&xs[d]);
        float4 wv = *(const float4*)(WT + o * 768 + d);
        a += xv.x * wv.x + xv.y * wv.y + xv.z * wv.z + xv.w * wv.w;
    }
    a += __shfl_xor(a, 1);
    a += __shfl_xor(a, 2);
    a += __shfl_xor(a, 4);
    if (part == 0) {
        int v = o >> 4, p = (o >> 2) & 3, q = o & 3;
        int hh = (n >> 5) * 4 + p, ww = (n & 31) * 4 + q;
        int b = be >> 1, e = be & 1;
        out[(((b * 2 + v) * 64 + hh) * 128 + ww) * 2 + e] = a;
    }
}

// ---------- workspace layout (bytes) ----------
#define WS_WQKVT 0
#define WS_WOT   (WS_WQKVT + 8 * 2304 * 768 * 2)
#define WS_W1T   (WS_WOT   + 8 * 768 * 768 * 2)
#define WS_W2T   (WS_W1T   + 8 * 3072 * 768 * 2)
#define WS_NWT   (WS_W2T   + 8 * 768 * 3072 * 2)
#define WS_WOUTT (WS_NWT   + 768 * 768 * 2)
#define WS_X     (WS_WOUTT + 32 * 768 * 4)
#define WS_H     (WS_X     + 8192 * 768 * 4)
#define WS_QKV   (WS_H     + 8192 * 768 * 2)
#define WS_O     (WS_QKV   + 8192 * 2304 * 2)
#define WS_G     (WS_O     + 8192 * 768 * 2)   // g also aliases z_bf16 (disjoint lifetimes)

extern "C" void kernel_launch(void* const* d_in, const int* in_sizes, int n_in,
                              void* d_out, int out_size, void* d_ws, size_t ws_size,
                              hipStream_t stream) {
    const float* fields   = (const float*)d_in[0];
    const int*   visible  = (const int*)d_in[1];
    const float* z        = (const float*)d_in[2];
    const float* W_in     = (const float*)d_in[3];
    const float* W_out    = (const float*)d_in[4];
    const float* noise_W  = (const float*)d_in[5];
    const float* noise_b  = (const float*)d_in[6];
    const float* mask_emb = (const float*)d_in[7];
    const float* pos_emb  = (const float*)d_in[8];
    const float* ln1_s    = (const float*)d_in[9];
    const float* ln1_b    = (const float*)d_in[10];
    const float* Wqkv     = (const float*)d_in[11];
    const float* bqkv     = (const float*)d_in[12];
    const float* Wo       = (const float*)d_in[13];
    const float* bo       = (const float*)d_in[14];
    const float* ln2_s    = (const float*)d_in[15];
    const float* ln2_b    = (const float*)d_in[16];
    const float* W1       = (const float*)d_in[17];
    const float* b1       = (const float*)d_in[18];
    const float* W2       = (const float*)d_in[19];
    const float* b2       = (const float*)d_in[20];
    float* out = (float*)d_out;
    char* ws = (char*)d_ws;

    ushort_t* wqkvT = (ushort_t*)(ws + WS_WQKVT);
    ushort_t* woT   = (ushort_t*)(ws + WS_WOT);
    ushort_t* w1T   = (ushort_t*)(ws + WS_W1T);
    ushort_t* w2T   = (ushort_t*)(ws + WS_W2T);
    ushort_t* nWT   = (ushort_t*)(ws + WS_NWT);
    float*    woutT = (float*)(ws + WS_WOUTT);
    float*    x     = (float*)(ws + WS_X);
    ushort_t* hbuf  = (ushort_t*)(ws + WS_H);
    ushort_t* qkv   = (ushort_t*)(ws + WS_QKV);
    ushort_t* obuf  = (ushort_t*)(ws + WS_O);
    ushort_t* gbuf  = (ushort_t*)(ws + WS_G);
    ushort_t* zbf   = gbuf;   // alias: z_bf16 dead before first MLP1

    // ---- weight prep ----
    wtrans_k<<<256, 256, 0, stream>>>(noise_W, nWT, 768, 768);
    for (int l = 0; l < 8; l++) {
        wtrans_k<<<256, 256, 0, stream>>>(Wqkv + l * 768 * 2304, wqkvT + l * 2304 * 768, 768, 2304);
        wtrans_k<<<256, 256, 0, stream>>>(Wo   + l * 768 * 768,  woT   + l * 768 * 768,  768, 768);
        wtrans_k<<<256, 256, 0, stream>>>(W1   + l * 768 * 3072, w1T   + l * 3072 * 768, 768, 3072);
        wtrans_k<<<256, 256, 0, stream>>>(W2   + l * 3072 * 768, w2T   + l * 768 * 3072, 3072, 768);
    }
    wouttrans_k<<<96, 256, 0, stream>>>(W_out, woutT);
    convbf_k<<<2048, 256, 0, stream>>>(z, zbf, 16 * 512 * 768 / 4);

    // ---- embedding + noise ----
    embed_k<<<16 * 512, 256, 0, stream>>>(fields, visible, W_in, mask_emb, pos_emb, x);
    gemm_bt<float, true, false><<<dim3(6, 64), 256, 0, stream>>>(zbf, nWT, noise_b, x, x, 8192, 768, 768);

    // ---- transformer layers ----
    for (int l = 0; l < 8; l++) {
        ln_k<<<2048, 256, 0, stream>>>(x, ln1_s + l * 768, ln1_b + l * 768, hbuf);
        gemm_bt<ushort_t, false, false><<<dim3(18, 64), 256, 0, stream>>>(
            hbuf, wqkvT + l * 2304 * 768, bqkv + l * 2304, nullptr, qkv, 8192, 2304, 768);
        attn_k<<<16 * 12 * 32, 256, 0, stream>>>(qkv, obuf);
        gemm_bt<float, true, false><<<dim3(6, 64), 256, 0, stream>>>(
            obuf, woT + l * 768 * 768, bo + l * 768, x, x, 8192, 768, 768);
        ln_k<<<2048, 256, 0, stream>>>(x, ln2_s + l * 768, ln2_b + l * 768, hbuf);
        gemm_bt<ushort_t, false, true><<<dim3(24, 64), 256, 0, stream>>>(
            hbuf, w1T + l * 3072 * 768, b1 + l * 3072, nullptr, gbuf, 8192, 3072, 768);
        gemm_bt<float, true, false><<<dim3(6, 64), 256, 0, stream>>>(
            gbuf, w2T + l * 768 * 3072, b2 + l * 768, x, x, 8192, 768, 3072);
    }

    // ---- output projection ----
    outproj_k<<<16 * 512, 256, 0, stream>>>(x, woutT, out);
}

// Round 3
// 3047.072 us; speedup vs baseline: 2.2357x; 2.2357x over previous
//
#include <hip/hip_runtime.h>

typedef unsigned short ushort_t;
typedef __bf16 bf16x8 __attribute__((ext_vector_type(8)));
typedef float f32x4 __attribute__((ext_vector_type(4)));
typedef unsigned short ushort8v __attribute__((ext_vector_type(8)));

// ---------- helpers ----------
__device__ __forceinline__ ushort_t f2bf(float f) {
    unsigned int u = __float_as_uint(f);
    u += 0x7FFFu + ((u >> 16) & 1u);          // RNE
    return (ushort_t)(u >> 16);
}
__device__ __forceinline__ float bf2f(ushort_t u) {
    return __uint_as_float(((unsigned int)u) << 16);
}
__device__ __forceinline__ float gelu_tanh(float x) {
    float x3 = x * x * x;
    float u = 0.7978845608028654f * (x + 0.044715f * x3);
    return 0.5f * x * (1.0f + tanhf(u));
}
__device__ __forceinline__ void store_out(float* p, float v)    { *p = v; }
__device__ __forceinline__ void store_out(ushort_t* p, float v) { *p = f2bf(v); }

// ---------- weight transpose + fp32->bf16:  W[K][N] -> WT[N][K] ----------
__global__ __launch_bounds__(256) void wtrans_k(const float* __restrict__ W,
                                                ushort_t* __restrict__ WT,
                                                int K, int N) {
    int nk = K >> 3;
    int total = (N >> 6) * nk;
    int gw = (blockIdx.x * 256 + threadIdx.x) >> 6;
    int nw = (gridDim.x * 256) >> 6;
    int lane = threadIdx.x & 63;
    for (int c = gw; c < total; c += nw) {
        int kb = c % nk, nb = c / nk;
        int n = nb * 64 + lane, k0 = kb * 8;
        ushort_t t0 = f2bf(W[(k0 + 0) * N + n]);
        ushort_t t1 = f2bf(W[(k0 + 1) * N + n]);
        ushort_t t2 = f2bf(W[(k0 + 2) * N + n]);
        ushort_t t3 = f2bf(W[(k0 + 3) * N + n]);
        ushort_t t4 = f2bf(W[(k0 + 4) * N + n]);
        ushort_t t5 = f2bf(W[(k0 + 5) * N + n]);
        ushort_t t6 = f2bf(W[(k0 + 6) * N + n]);
        ushort_t t7 = f2bf(W[(k0 + 7) * N + n]);
        int4 pk;
        pk.x = (int)t0 | ((int)t1 << 16);
        pk.y = (int)t2 | ((int)t3 << 16);
        pk.z = (int)t4 | ((int)t5 << 16);
        pk.w = (int)t6 | ((int)t7 << 16);
        *(int4*)(WT + n * K + k0) = pk;
    }
}

// ---------- W_out (V,D,PH,PW) -> WT[v*16+p*4+q][d]  (fp32) ----------
__global__ void wouttrans_k(const float* __restrict__ W_out, float* __restrict__ WT) {
    int i = blockIdx.x * 256 + threadIdx.x;
    if (i >= 32 * 768) return;
    int o = i / 768, d = i - o * 768;
    int v = o >> 4, p = (o >> 2) & 3, q = o & 3;
    WT[i] = W_out[((v * 768 + d) * 4 + p) * 4 + q];
}

// ---------- fp32 -> bf16 convert (vectorized) ----------
__global__ void convbf_k(const float* __restrict__ src, ushort_t* __restrict__ dst, int nq) {
    int i = blockIdx.x * 256 + threadIdx.x;
    int stride = gridDim.x * 256;
    for (; i < nq; i += stride) {
        float4 v = *(const float4*)(src + i * 4);
        int2 pk;
        pk.x = (int)f2bf(v.x) | ((int)f2bf(v.y) << 16);
        pk.y = (int)f2bf(v.z) | ((int)f2bf(v.w) << 16);
        *(int2*)(dst + i * 4) = pk;
    }
}

// ---------- embedding: patch einsum + mask + pos_emb -> x (fp32) ----------
__global__ __launch_bounds__(256) void embed_k(const float* __restrict__ fields,
                                               const int* __restrict__ visible,
                                               const float* __restrict__ W_in,
                                               const float* __restrict__ mask_emb,
                                               const float* __restrict__ pos_emb,
                                               float* __restrict__ x) {
    int bid = blockIdx.x;               // be*512 + n
    int be = bid >> 9, n = bid & 511;
    int b = be >> 1;                    // E = 2
    int hh = n >> 5, w = n & 31;
    __shared__ float fs[32];
    int t = threadIdx.x;
    if (t < 32) {
        int v = t >> 4, p = (t >> 2) & 3, q = t & 3;
        fs[t] = fields[((b * 2 + v) * 64 + hh * 4 + p) * 128 + w * 4 + q];
    }
    __syncthreads();
    int vis = visible[b * 512 + n];
    for (int d = t; d < 768; d += 256) {
        float a;
        if (vis) {
            a = 0.f;
            #pragma unroll
            for (int j = 0; j < 32; j++) a += fs[j] * W_in[j * 768 + d];
        } else {
            a = mask_emb[d];
        }
        x[(be * 512 + n) * 768 + d] = a + pos_emb[n * 768 + d];
    }
}

// ---------- LayerNorm: fp32 x -> bf16 h (1 wave / row) ----------
__global__ __launch_bounds__(256) void ln_k(const float* __restrict__ x,
                                            const float* __restrict__ s,
                                            const float* __restrict__ b,
                                            ushort_t* __restrict__ h) {
    int row = blockIdx.x * 4 + (threadIdx.x >> 6);
    int lane = threadIdx.x & 63;
    const float* xr = x + row * 768;
    float4 v[3];
    #pragma unroll
    for (int i = 0; i < 3; i++) v[i] = *(const float4*)(xr + (lane + 64 * i) * 4);
    float sum = 0.f;
    #pragma unroll
    for (int i = 0; i < 3; i++) sum += v[i].x + v[i].y + v[i].z + v[i].w;
    #pragma unroll
    for (int off = 32; off; off >>= 1) sum += __shfl_xor(sum, off);
    float mu = sum * (1.f / 768.f);
    float vs = 0.f;
    #pragma unroll
    for (int i = 0; i < 3; i++) {
        float dx = v[i].x - mu, dy = v[i].y - mu, dz = v[i].z - mu, dw = v[i].w - mu;
        vs += dx * dx + dy * dy + dz * dz + dw * dw;
    }
    #pragma unroll
    for (int off = 32; off; off >>= 1) vs += __shfl_xor(vs, off);
    float rstd = rsqrtf(vs * (1.f / 768.f) + 1e-5f);
    #pragma unroll
    for (int i = 0; i < 3; i++) {
        int c = (lane + 64 * i) * 4;
        float4 sv = *(const float4*)(s + c);
        float4 bv = *(const float4*)(b + c);
        int2 pk;
        pk.x = (int)f2bf((v[i].x - mu) * rstd * sv.x + bv.x)
             | ((int)f2bf((v[i].y - mu) * rstd * sv.y + bv.y) << 16);
        pk.y = (int)f2bf((v[i].z - mu) * rstd * sv.z + bv.z)
             | ((int)f2bf((v[i].w - mu) * rstd * sv.w + bv.w) << 16);
        *(int2*)(h + row * 768 + c) = pk;
    }
}

// ---------- bf16 MFMA GEMM:  out = epi(A[M][K] @ BT[N][K]^T + bias (+res)) ----------
template <typename OutT, bool RES, bool GELU>
__global__ __launch_bounds__(256) void gemm_bt(const ushort_t* __restrict__ A,
                                               const ushort_t* __restrict__ BT,
                                               const float* __restrict__ bias,
                                               const float* __restrict__ res,
                                               OutT* __restrict__ out,
                                               int M, int N, int K) {
    __shared__ ushort_t As[128][40];
    __shared__ ushort_t Bs[128][40];
    int t = threadIdx.x;
    int lane = t & 63;
    int wid = t >> 6;
    int wr = wid >> 1, wc = wid & 1;   // 2x2 waves, 64x64 out each
    int m0 = blockIdx.y * 128, n0 = blockIdx.x * 128;
    f32x4 acc[4][4];
    #pragma unroll
    for (int m = 0; m < 4; m++)
        #pragma unroll
        for (int n = 0; n < 4; n++) acc[m][n] = (f32x4){0.f, 0.f, 0.f, 0.f};

    int sr = t >> 2;            // 0..63
    int sk = (t & 3) * 8;       // 0,8,16,24
    for (int k0 = 0; k0 < K; k0 += 32) {
        int4 a0 = *(const int4*)(A + (m0 + sr) * K + k0 + sk);
        int4 a1 = *(const int4*)(A + (m0 + sr + 64) * K + k0 + sk);
        int4 b0 = *(const int4*)(BT + (n0 + sr) * K + k0 + sk);
        int4 b1 = *(const int4*)(BT + (n0 + sr + 64) * K + k0 + sk);
        __syncthreads();
        *(int4*)(&As[sr][sk]) = a0;
        *(int4*)(&As[sr + 64][sk]) = a1;
        *(int4*)(&Bs[sr][sk]) = b0;
        *(int4*)(&Bs[sr + 64][sk]) = b1;
        __syncthreads();
        bf16x8 af[4], bf[4];
        #pragma unroll
        for (int m = 0; m < 4; m++)
            af[m] = *(const bf16x8*)(&As[wr * 64 + m * 16 + (lane & 15)][(lane >> 4) * 8]);
        #pragma unroll
        for (int n = 0; n < 4; n++)
            bf[n] = *(const bf16x8*)(&Bs[wc * 64 + n * 16 + (lane & 15)][(lane >> 4) * 8]);
        #pragma unroll
        for (int m = 0; m < 4; m++)
            #pragma unroll
            for (int n = 0; n < 4; n++)
                acc[m][n] = __builtin_amdgcn_mfma_f32_16x16x32_bf16(af[m], bf[n], acc[m][n], 0, 0, 0);
    }
    __syncthreads();
    int rq = lane >> 4, cl = lane & 15;
    #pragma unroll
    for (int m = 0; m < 4; m++) {
        #pragma unroll
        for (int n = 0; n < 4; n++) {
            int col = n0 + wc * 64 + n * 16 + cl;
            float bv = bias[col];
            #pragma unroll
            for (int r = 0; r < 4; r++) {
                int row = m0 + wr * 64 + m * 16 + rq * 4 + r;
                float v = acc[m][n][r] + bv;
                if (RES) v += res[row * N + col];
                if (GELU) v = gelu_tanh(v);
                store_out(out + row * N + col, v);
            }
        }
    }
}

// ---------- V transpose: qkv V-part -> vt[beh][64 d][512 tok] (bf16) ----------
__global__ __launch_bounds__(256) void vtrans_k(const ushort_t* __restrict__ qkv,
                                                ushort_t* __restrict__ vt) {
    int beh = blockIdx.x;              // 0..191
    int kq = blockIdx.y;               // 0..3 (128-token quarter)
    int be = beh / 12, h = beh % 12;
    int t = threadIdx.x;
    __shared__ ushort_t Vs[128][72];
    int tok0 = t >> 3, ch = t & 7;
    const ushort_t* src = qkv + (be * 512 + kq * 128) * 2304 + 1536 + h * 64;
    #pragma unroll
    for (int it = 0; it < 4; it++) {
        int tok = it * 32 + tok0;
        *(ushort8v*)(&Vs[tok][ch * 8]) = *(const ushort8v*)(src + tok * 2304 + ch * 8);
    }
    __syncthreads();
    int d = t >> 2, tg = t & 3;
    ushort8v ov[4];
    #pragma unroll
    for (int j = 0; j < 4; j++)
        #pragma unroll
        for (int i = 0; i < 8; i++)
            ov[j][i] = Vs[tg * 32 + j * 8 + i][d];
    ushort_t* dst = vt + (beh * 64 + d) * 512 + kq * 128 + tg * 32;
    #pragma unroll
    for (int j = 0; j < 4; j++)
        *(ushort8v*)(dst + j * 8) = ov[j];
}

// ---------- MFMA attention: block = (qtile 64 rows, be*12+h), 4 waves x 16 q ----------
__global__ __launch_bounds__(256, 1) void attn_k(const ushort_t* __restrict__ qkv,
                                                 const ushort_t* __restrict__ vt,
                                                 ushort_t* __restrict__ o) {
    int qt = blockIdx.x;               // 0..7
    int beh = blockIdx.y;              // 0..191
    int be = beh / 12, h = beh % 12;
    int t = threadIdx.x;
    int w = t >> 6;
    int lane = t & 63;
    int c = lane & 15, g = lane >> 4;

    __shared__ __align__(16) char lds[34816];
    ushort_t (*Ks)[72]   = (ushort_t (*)[72])lds;             // [128][72]  pass 1
    ushort_t (*Ph)[136]  = (ushort_t (*)[136])lds;            // [64][136]  pass 2 (aliases Ks)
    ushort_t (*Vtq)[136] = (ushort_t (*)[136])(lds + 17408);  // [64][136]  pass 2

    // Q fragments (B-operand): q = qt*64 + w*16 + c ; d = kd*32 + g*8 + j
    const ushort_t* qptr = qkv + ((be * 512 + qt * 64 + w * 16 + c) * 2304) + h * 64 + g * 8;
    bf16x8 qf0 = *(const bf16x8*)(qptr);
    bf16x8 qf1 = *(const bf16x8*)(qptr + 32);

    f32x4 st[32];                      // S^T[key][q]: key = tile*16 + g*4 + r, q = c
    #pragma unroll
    for (int i = 0; i < 32; i++) st[i] = (f32x4){0.f, 0.f, 0.f, 0.f};

    // ---- pass 1: S^T = K @ Q^T (row = key, col = q) ----
    const ushort_t* kbase = qkv + (be * 512) * 2304 + 768 + h * 64;
    int srow = t >> 3, sch = t & 7;
    #pragma unroll
    for (int kq = 0; kq < 4; kq++) {
        __syncthreads();
        #pragma unroll
        for (int it = 0; it < 4; it++) {
            int tok = it * 32 + srow;
            *(ushort8v*)(&Ks[tok][sch * 8]) =
                *(const ushort8v*)(kbase + (kq * 128 + tok) * 2304 + sch * 8);
        }
        __syncthreads();
        #pragma unroll
        for (int kt = 0; kt < 8; kt++) {
            bf16x8 kf0 = *(const bf16x8*)(&Ks[kt * 16 + c][g * 8]);
            bf16x8 kf1 = *(const bf16x8*)(&Ks[kt * 16 + c][32 + g * 8]);
            st[kq * 8 + kt] = __builtin_amdgcn_mfma_f32_16x16x32_bf16(kf0, qf0, st[kq * 8 + kt], 0, 0, 0);
            st[kq * 8 + kt] = __builtin_amdgcn_mfma_f32_16x16x32_bf16(kf1, qf1, st[kq * 8 + kt], 0, 0, 0);
        }
    }

    // ---- softmax over keys (in-lane 128 vals + xor16/xor32 across g-groups) ----
    float mx = -3.4e38f;
    #pragma unroll
    for (int i = 0; i < 32; i++)
        #pragma unroll
        for (int r = 0; r < 4; r++) mx = fmaxf(mx, st[i][r]);
    mx = fmaxf(mx, __shfl_xor(mx, 16));
    mx = fmaxf(mx, __shfl_xor(mx, 32));
    float sum = 0.f;
    #pragma unroll
    for (int i = 0; i < 32; i++)
        #pragma unroll
        for (int r = 0; r < 4; r++) {
            float p = __expf(0.125f * (st[i][r] - mx));
            st[i][r] = p;
            sum += p;
        }
    sum += __shfl_xor(sum, 16);
    sum += __shfl_xor(sum, 32);
    float rinv = 1.f / sum;

    // ---- pass 2: O = P @ V via Ph (LDS transpose) and Vt staging ----
    f32x4 oc[4];
    #pragma unroll
    for (int i = 0; i < 4; i++) oc[i] = (f32x4){0.f, 0.f, 0.f, 0.f};
    const ushort_t* vbase = vt + beh * 64 * 512;
    int vd = t >> 4, vch = t & 15;
    #pragma unroll
    for (int kq = 0; kq < 4; kq++) {
        __syncthreads();
        // write P quarter (each wave writes only its own 16 q-rows)
        #pragma unroll
        for (int tl = 0; tl < 8; tl++) {
            int tt = kq * 8 + tl;
            unsigned int w0 = (unsigned int)f2bf(st[tt][0] * rinv)
                            | ((unsigned int)f2bf(st[tt][1] * rinv) << 16);
            unsigned int w1 = (unsigned int)f2bf(st[tt][2] * rinv)
                            | ((unsigned int)f2bf(st[tt][3] * rinv) << 16);
            uint2 pk; pk.x = w0; pk.y = w1;
            *(uint2*)(&Ph[w * 16 + c][tl * 16 + g * 4]) = pk;
        }
        // stage Vt quarter (cooperative, coalesced)
        #pragma unroll
        for (int it = 0; it < 4; it++) {
            int d = it * 16 + vd;
            *(ushort8v*)(&Vtq[d][vch * 8]) =
                *(const ushort8v*)(vbase + d * 512 + kq * 128 + vch * 8);
        }
        __syncthreads();
        #pragma unroll
        for (int kt = 0; kt < 4; kt++) {
            bf16x8 pa = *(const bf16x8*)(&Ph[w * 16 + c][kt * 32 + g * 8]);
            #pragma unroll
            for (int dt = 0; dt < 4; dt++) {
                bf16x8 vb = *(const bf16x8*)(&Vtq[dt * 16 + c][kt * 32 + g * 8]);
                oc[dt] = __builtin_amdgcn_mfma_f32_16x16x32_bf16(pa, vb, oc[dt], 0, 0, 0);
            }
        }
    }

    // ---- store O (row = g*4+r, col = dt*16+c) ----
    ushort_t* obase = o + (be * 512 + qt * 64 + w * 16) * 768 + h * 64;
    #pragma unroll
    for (int dt = 0; dt < 4; dt++)
        #pragma unroll
        for (int r = 0; r < 4; r++)
            obase[(g * 4 + r) * 768 + dt * 16 + c] = f2bf(oc[dt][r]);
}

// ---------- output projection ----------
__global__ __launch_bounds__(256) void outproj_k(const float* __restrict__ x,
                                                 const float* __restrict__ WT,
                                                 float* __restrict__ out) {
    int bid = blockIdx.x;              // be*512 + n
    int be = bid >> 9, n = bid & 511;
    __shared__ float xs[768];
    int t = threadIdx.x;
    if (t < 192) *(float4*)(&xs[t * 4]) = *(const float4*)(x + bid * 768 + t * 4);
    __syncthreads();
    int o = t >> 3, part = t & 7;      // 32 outputs x 8 partial threads
    float a = 0.f;
    #pragma unroll
    for (int i = 0; i < 24; i++) {
        int d = (part + 8 * i) * 4;
        float4 xv = *(const float4*)(&xs[d]);
        float4 wv = *(const float4*)(WT + o * 768 + d);
        a += xv.x * wv.x + xv.y * wv.y + xv.z * wv.z + xv.w * wv.w;
    }
    a += __shfl_xor(a, 1);
    a += __shfl_xor(a, 2);
    a += __shfl_xor(a, 4);
    if (part == 0) {
        int v = o >> 4, p = (o >> 2) & 3, q = o & 3;
        int hh = (n >> 5) * 4 + p, ww = (n & 31) * 4 + q;
        int b = be >> 1, e = be & 1;
        out[(((b * 2 + v) * 64 + hh) * 128 + ww) * 2 + e] = a;
    }
}

// ---------- workspace layout (bytes) ----------
#define WS_WQKVT 0
#define WS_WOT   (WS_WQKVT + 8 * 2304 * 768 * 2)
#define WS_W1T   (WS_WOT   + 8 * 768 * 768 * 2)
#define WS_W2T   (WS_W1T   + 8 * 3072 * 768 * 2)
#define WS_NWT   (WS_W2T   + 8 * 768 * 3072 * 2)
#define WS_WOUTT (WS_NWT   + 768 * 768 * 2)
#define WS_X     (WS_WOUTT + 32 * 768 * 4)
#define WS_H     (WS_X     + 8192 * 768 * 4)
#define WS_QKV   (WS_H     + 8192 * 768 * 2)
#define WS_O     (WS_QKV   + 8192 * 2304 * 2)
#define WS_G     (WS_O     + 8192 * 768 * 2)   // g also aliases z_bf16 (disjoint lifetimes)
#define WS_VT    (WS_G     + 8192 * 3072 * 2)

extern "C" void kernel_launch(void* const* d_in, const int* in_sizes, int n_in,
                              void* d_out, int out_size, void* d_ws, size_t ws_size,
                              hipStream_t stream) {
    const float* fields   = (const float*)d_in[0];
    const int*   visible  = (const int*)d_in[1];
    const float* z        = (const float*)d_in[2];
    const float* W_in     = (const float*)d_in[3];
    const float* W_out    = (const float*)d_in[4];
    const float* noise_W  = (const float*)d_in[5];
    const float* noise_b  = (const float*)d_in[6];
    const float* mask_emb = (const float*)d_in[7];
    const float* pos_emb  = (const float*)d_in[8];
    const float* ln1_s    = (const float*)d_in[9];
    const float* ln1_b    = (const float*)d_in[10];
    const float* Wqkv     = (const float*)d_in[11];
    const float* bqkv     = (const float*)d_in[12];
    const float* Wo       = (const float*)d_in[13];
    const float* bo       = (const float*)d_in[14];
    const float* ln2_s    = (const float*)d_in[15];
    const float* ln2_b    = (const float*)d_in[16];
    const float* W1       = (const float*)d_in[17];
    const float* b1       = (const float*)d_in[18];
    const float* W2       = (const float*)d_in[19];
    const float* b2       = (const float*)d_in[20];
    float* out = (float*)d_out;
    char* ws = (char*)d_ws;

    ushort_t* wqkvT = (ushort_t*)(ws + WS_WQKVT);
    ushort_t* woT   = (ushort_t*)(ws + WS_WOT);
    ushort_t* w1T   = (ushort_t*)(ws + WS_W1T);
    ushort_t* w2T   = (ushort_t*)(ws + WS_W2T);
    ushort_t* nWT   = (ushort_t*)(ws + WS_NWT);
    float*    woutT = (float*)(ws + WS_WOUTT);
    float*    x     = (float*)(ws + WS_X);
    ushort_t* hbuf  = (ushort_t*)(ws + WS_H);
    ushort_t* qkv   = (ushort_t*)(ws + WS_QKV);
    ushort_t* obuf  = (ushort_t*)(ws + WS_O);
    ushort_t* gbuf  = (ushort_t*)(ws + WS_G);
    ushort_t* vt    = (ushort_t*)(ws + WS_VT);
    ushort_t* zbf   = gbuf;   // alias: z_bf16 dead before first MLP1

    // ---- weight prep ----
    wtrans_k<<<256, 256, 0, stream>>>(noise_W, nWT, 768, 768);
    for (int l = 0; l < 8; l++) {
        wtrans_k<<<256, 256, 0, stream>>>(Wqkv + l * 768 * 2304, wqkvT + l * 2304 * 768, 768, 2304);
        wtrans_k<<<256, 256, 0, stream>>>(Wo   + l * 768 * 768,  woT   + l * 768 * 768,  768, 768);
        wtrans_k<<<256, 256, 0, stream>>>(W1   + l * 768 * 3072, w1T   + l * 3072 * 768, 768, 3072);
        wtrans_k<<<256, 256, 0, stream>>>(W2   + l * 3072 * 768, w2T   + l * 768 * 3072, 3072, 768);
    }
    wouttrans_k<<<96, 256, 0, stream>>>(W_out, woutT);
    convbf_k<<<2048, 256, 0, stream>>>(z, zbf, 16 * 512 * 768 / 4);

    // ---- embedding + noise ----
    embed_k<<<16 * 512, 256, 0, stream>>>(fields, visible, W_in, mask_emb, pos_emb, x);
    gemm_bt<float, true, false><<<dim3(6, 64), 256, 0, stream>>>(zbf, nWT, noise_b, x, x, 8192, 768, 768);

    // ---- transformer layers ----
    for (int l = 0; l < 8; l++) {
        ln_k<<<2048, 256, 0, stream>>>(x, ln1_s + l * 768, ln1_b + l * 768, hbuf);
        gemm_bt<ushort_t, false, false><<<dim3(18, 64), 256, 0, stream>>>(
            hbuf, wqkvT + l * 2304 * 768, bqkv + l * 2304, nullptr, qkv, 8192, 2304, 768);
        vtrans_k<<<dim3(192, 4), 256, 0, stream>>>(qkv, vt);
        attn_k<<<dim3(8, 192), 256, 0, stream>>>(qkv, vt, obuf);
        gemm_bt<float, true, false><<<dim3(6, 64), 256, 0, stream>>>(
            obuf, woT + l * 768 * 768, bo + l * 768, x, x, 8192, 768, 768);
        ln_k<<<2048, 256, 0, stream>>>(x, ln2_s + l * 768, ln2_b + l * 768, hbuf);
        gemm_bt<ushort_t, false, true><<<dim3(24, 64), 256, 0, stream>>>(
            hbuf, w1T + l * 3072 * 768, b1 + l * 3072, nullptr, gbuf, 8192, 3072, 768);
        gemm_bt<float, true, false><<<dim3(6, 64), 256, 0, stream>>>(
            gbuf, w2T + l * 768 * 3072, b2 + l * 768, x, x, 8192, 768, 3072);
    }

    // ---- output projection ----
    outproj_k<<<16 * 512, 256, 0, stream>>>(x, woutT, out);
}